// Round 11
// baseline (315.105 us; speedup 1.0000x reference)
//
#include <hip/hip_runtime.h>
#include <cstddef>

#define NN   50000
#define EE   800000
#define TOTE 850000      // EE + NN self loops
#define INC  256
#define HEADS 8
#define F1   512         // HEADS*64
#define OUTC 64
#define NB   ((NN + 255) / 256)   // scan blocks = 196

// prelude partition (blocks)
#define PB_CVTX   ((NN * INC / 8 + 255) / 256)        // 6250
#define PB_CVTW1  ((INC * F1 + 255) / 256)            // 512
#define PB_CVTW2  ((F1 * OUTC + 255) / 256)           // 128
#define PB_COUNT  ((TOTE + 255) / 256)                // 3321

typedef unsigned short ushort_t;
typedef unsigned int uint_t;
typedef __attribute__((ext_vector_type(8))) short short8;
typedef __attribute__((ext_vector_type(4))) float f32x4;

__device__ __forceinline__ ushort_t f32_to_bf16_rne(float f) {
  uint_t u = __float_as_uint(f);
  u += 0x7fffu + ((u >> 16) & 1u);
  return (ushort_t)(u >> 16);
}
__device__ __forceinline__ float bf16lo_to_f32(uint_t u) {
  return __uint_as_float(u << 16);
}
__device__ __forceinline__ float bf16hi_to_f32(uint_t u) {
  return __uint_as_float(u & 0xffff0000u);
}
// leaky_relu(x, 0.2) = max(x, 0.2x)  (valid for slope<1)
__device__ __forceinline__ float lrelu(float x) { return fmaxf(x, 0.2f * x); }

// async global->LDS, 16B per lane; LDS dest is wave-uniform base + lane*16
__device__ __forceinline__ void gload16(const ushort_t* g, ushort_t* l) {
  __builtin_amdgcn_global_load_lds(
      (const __attribute__((address_space(1))) void*)g,
      (__attribute__((address_space(3))) void*)l, 16, 0, 0);
}

// bijective XCD chunk swizzle (m204): valid for any nwg
__device__ __forceinline__ int xcd_swz(int p, int nwg) {
  int q = nwg >> 3, r = nwg & 7, x = p & 7;
  return (x < r ? x * (q + 1) : r * (q + 1) + (x - r) * q) + (p >> 3);
}

// ------- fused prelude: cvt_x | cvtT(W1) | cvtT(W2) | count (independent) ----
__global__ __launch_bounds__(256)
void prelude_kernel(const float* __restrict__ x, ushort_t* __restrict__ xbf,
                    const float* __restrict__ W1, ushort_t* __restrict__ W1T,
                    const float* __restrict__ W2, ushort_t* __restrict__ W2T,
                    const int* __restrict__ dsts, int* __restrict__ deg) {
  int b = blockIdx.x;
  if (b < PB_CVTX) {
    long i = ((long)b * 256 + threadIdx.x) * 8;
    if (i >= (long)NN * INC) return;
    float4 v0 = *reinterpret_cast<const float4*>(x + i);
    float4 v1 = *reinterpret_cast<const float4*>(x + i + 4);
    ushort_t p[8] = {f32_to_bf16_rne(v0.x), f32_to_bf16_rne(v0.y),
                     f32_to_bf16_rne(v0.z), f32_to_bf16_rne(v0.w),
                     f32_to_bf16_rne(v1.x), f32_to_bf16_rne(v1.y),
                     f32_to_bf16_rne(v1.z), f32_to_bf16_rne(v1.w)};
    *reinterpret_cast<uint4*>(xbf + i) = *reinterpret_cast<uint4*>(p);
    return;
  }
  b -= PB_CVTX;
  if (b < PB_CVTW1) {
    int i = b * 256 + threadIdx.x;
    if (i >= INC * F1) return;
    int k = i / F1, n = i % F1;
    W1T[(size_t)n * INC + k] = f32_to_bf16_rne(W1[i]);
    return;
  }
  b -= PB_CVTW1;
  if (b < PB_CVTW2) {
    int i = b * 256 + threadIdx.x;
    if (i >= F1 * OUTC) return;
    int k = i / OUTC, n = i % OUTC;
    W2T[(size_t)n * F1 + k] = f32_to_bf16_rne(W2[i]);
    return;
  }
  b -= PB_CVTW2;
  {
    int e = b * 256 + threadIdx.x;
    if (e >= TOTE) return;
    int dst = (e < EE) ? dsts[e] : (e - EE);
    atomicAdd(&deg[dst], 1);
  }
}

// ---- MFMA GEMM, BM=128 BN=128 BK=64, 4 waves (each wave owns a 64x64
// quadrant = exactly one head). A bf16 [M,K], BT bf16 [Nn,K]. Layer-1 GEMM.
__global__ __launch_bounds__(256, 2)
void gemm_mfma128(const ushort_t* __restrict__ A, const ushort_t* __restrict__ BT,
                  const float* __restrict__ a_src, const float* __restrict__ a_dst,
                  ushort_t* __restrict__ Cbf, float* __restrict__ AS,
                  float* __restrict__ AD, int M, int K, int Nn, int nheads) {
  __shared__ __align__(16) ushort_t sA[128 * 64];  // rows of 128B, slot-swizzled
  __shared__ __align__(16) ushort_t sB[128 * 64];
  const int tid = threadIdx.x;
  const int w = tid >> 6, lane = tid & 63;

  const int l = xcd_swz(blockIdx.x, gridDim.x);
  const int nColB = Nn >> 7;
  const int rowBase = (l / nColB) * 128;
  const int colBase = (l % nColB) * 128;

  const int l8 = lane >> 3;
  const int srcslot = (lane & 7) ^ l8;
  size_t aOff[4]; ushort_t* aLds[4];
  size_t bOff[4]; ushort_t* bLds[4];
  #pragma unroll
  for (int q = 0; q < 4; ++q) {
    int r0 = w * 32 + q * 8;
    int grow = rowBase + r0 + l8; if (grow > M - 1) grow = M - 1;
    aOff[q] = (size_t)grow * K + srcslot * 8;
    aLds[q] = sA + r0 * 64;
    bOff[q] = (size_t)(colBase + r0 + l8) * K + srcslot * 8;
    bLds[q] = sB + r0 * 64;
  }

  f32x4 acc[4][4];
  #pragma unroll
  for (int mf = 0; mf < 4; ++mf)
    #pragma unroll
    for (int cf = 0; cf < 4; ++cf)
      acc[mf][cf] = (f32x4){0.f, 0.f, 0.f, 0.f};

  const int wr = (w >> 1) * 64;   // wave quadrant row offset
  const int wc = (w & 1) * 64;    // wave quadrant col offset
  const int nkt = K >> 6;
  for (int kt = 0; kt < nkt; ++kt) {
    __syncthreads();
    #pragma unroll
    for (int q = 0; q < 4; ++q) gload16(A + aOff[q] + kt * 64, aLds[q]);
    #pragma unroll
    for (int q = 0; q < 4; ++q) gload16(BT + bOff[q] + kt * 64, bLds[q]);
    __syncthreads();
    #pragma unroll
    for (int ks = 0; ks < 2; ++ks) {
      const int sl = ks * 4 + (lane >> 4);
      short8 af[4], bfr[4];
      #pragma unroll
      for (int mf = 0; mf < 4; ++mf) {
        int row = wr + mf * 16 + (lane & 15);
        af[mf] = *reinterpret_cast<short8*>((char*)sA + row * 128 + ((sl ^ (row & 7)) << 4));
      }
      #pragma unroll
      for (int cf = 0; cf < 4; ++cf) {
        int col = wc + cf * 16 + (lane & 15);
        bfr[cf] = *reinterpret_cast<short8*>((char*)sB + col * 128 + ((sl ^ (col & 7)) << 4));
      }
      #pragma unroll
      for (int mf = 0; mf < 4; ++mf)
        #pragma unroll
        for (int cf = 0; cf < 4; ++cf)
          acc[mf][cf] = __builtin_amdgcn_mfma_f32_16x16x32_bf16(af[mf], bfr[cf], acc[mf][cf], 0, 0, 0);
    }
  }

  // epilogue: C/D layout col=lane&15, row=(lane>>4)*4+reg; wave = one head
  const int g = lane >> 4, c = lane & 15;
  const int head = (colBase + wc) >> 6;
  float asv[4], adv[4];
  #pragma unroll
  for (int cf = 0; cf < 4; ++cf) {
    asv[cf] = a_src[colBase + wc + cf * 16 + c];
    adv[cf] = a_dst[colBase + wc + cf * 16 + c];
  }
  #pragma unroll
  for (int mf = 0; mf < 4; ++mf) {
    #pragma unroll
    for (int r = 0; r < 4; ++r) {
      int row = rowBase + wr + mf * 16 + g * 4 + r;
      bool ok = row < M;
      float s = 0.f, d = 0.f;
      #pragma unroll
      for (int cf = 0; cf < 4; ++cf) {
        float v = acc[mf][cf][r];
        s = fmaf(v, asv[cf], s);
        d = fmaf(v, adv[cf], d);
        if (ok) Cbf[(size_t)row * Nn + colBase + wc + cf * 16 + c] = f32_to_bf16_rne(v);
      }
      #pragma unroll
      for (int off = 8; off > 0; off >>= 1) {
        s += __shfl_xor(s, off);
        d += __shfl_xor(d, off);
      }
      if (ok && c == 0) {
        AS[(size_t)row * nheads + head] = s;
        AD[(size_t)row * nheads + head] = d;
      }
    }
  }
}

// ---- MFMA GEMM, BM=128 BN=64 BK=64, 4 waves (layer-2 GEMM, Nn=64) ----------
__global__ __launch_bounds__(256, 2)
void gemm_mfma(const ushort_t* __restrict__ A, const ushort_t* __restrict__ BT,
               const float* __restrict__ a_src, const float* __restrict__ a_dst,
               ushort_t* __restrict__ Cbf, float* __restrict__ AS,
               float* __restrict__ AD, int M, int K, int Nn, int nheads) {
  __shared__ __align__(16) ushort_t sA[128 * 64];
  __shared__ __align__(16) ushort_t sB[64 * 64];
  const int tid = threadIdx.x;
  const int w = tid >> 6, lane = tid & 63;

  const int l = xcd_swz(blockIdx.x, gridDim.x);
  const int rowBase = (l / nheads) * 128;
  const int head = l % nheads;
  const int colBase = head * 64;

  const int l8 = lane >> 3;
  const int srcslot = (lane & 7) ^ l8;
  size_t aOff[4]; ushort_t* aLds[4];
  #pragma unroll
  for (int q = 0; q < 4; ++q) {
    int r0 = w * 32 + q * 8;
    int grow = rowBase + r0 + l8; if (grow > M - 1) grow = M - 1;
    aOff[q] = (size_t)grow * K + srcslot * 8;
    aLds[q] = sA + r0 * 64;
  }
  size_t bOff[2]; ushort_t* bLds[2];
  #pragma unroll
  for (int q = 0; q < 2; ++q) {
    int c0 = w * 16 + q * 8;
    bOff[q] = (size_t)(colBase + c0 + l8) * K + srcslot * 8;
    bLds[q] = sB + c0 * 64;
  }

  f32x4 acc[2][4];
  #pragma unroll
  for (int mf = 0; mf < 2; ++mf)
    #pragma unroll
    for (int cf = 0; cf < 4; ++cf)
      acc[mf][cf] = (f32x4){0.f, 0.f, 0.f, 0.f};

  const int nkt = K >> 6;
  for (int kt = 0; kt < nkt; ++kt) {
    __syncthreads();
    #pragma unroll
    for (int q = 0; q < 4; ++q) gload16(A + aOff[q] + kt * 64, aLds[q]);
    #pragma unroll
    for (int q = 0; q < 2; ++q) gload16(BT + bOff[q] + kt * 64, bLds[q]);
    __syncthreads();
    #pragma unroll
    for (int ks = 0; ks < 2; ++ks) {
      const int sl = ks * 4 + (lane >> 4);
      short8 af[2], bfr[4];
      #pragma unroll
      for (int mf = 0; mf < 2; ++mf) {
        int row = w * 32 + mf * 16 + (lane & 15);
        af[mf] = *reinterpret_cast<short8*>((char*)sA + row * 128 + ((sl ^ (row & 7)) << 4));
      }
      #pragma unroll
      for (int cf = 0; cf < 4; ++cf) {
        int col = cf * 16 + (lane & 15);
        bfr[cf] = *reinterpret_cast<short8*>((char*)sB + col * 128 + ((sl ^ (col & 7)) << 4));
      }
      #pragma unroll
      for (int mf = 0; mf < 2; ++mf)
        #pragma unroll
        for (int cf = 0; cf < 4; ++cf)
          acc[mf][cf] = __builtin_amdgcn_mfma_f32_16x16x32_bf16(af[mf], bfr[cf], acc[mf][cf], 0, 0, 0);
    }
  }

  const int g = lane >> 4, c = lane & 15;
  float asv[4], adv[4];
  #pragma unroll
  for (int cf = 0; cf < 4; ++cf) {
    asv[cf] = a_src[colBase + cf * 16 + c];
    adv[cf] = a_dst[colBase + cf * 16 + c];
  }
  #pragma unroll
  for (int mf = 0; mf < 2; ++mf) {
    #pragma unroll
    for (int r = 0; r < 4; ++r) {
      int row = rowBase + w * 32 + mf * 16 + g * 4 + r;
      bool ok = row < M;
      float s = 0.f, d = 0.f;
      #pragma unroll
      for (int cf = 0; cf < 4; ++cf) {
        float v = acc[mf][cf][r];
        s = fmaf(v, asv[cf], s);
        d = fmaf(v, adv[cf], d);
        if (ok) Cbf[(size_t)row * Nn + colBase + cf * 16 + c] = f32_to_bf16_rne(v);
      }
      #pragma unroll
      for (int off = 8; off > 0; off >>= 1) {
        s += __shfl_xor(s, off);
        d += __shfl_xor(d, off);
      }
      if (ok && c == 0) {
        AS[(size_t)row * nheads + head] = s;
        AD[(size_t)row * nheads + head] = d;
      }
    }
  }
}

// ---------------- CSR build --------------------------------------------------
__global__ __launch_bounds__(256)
void scanA_kernel(const int* __restrict__ deg, int* __restrict__ rowptr,
                  int* __restrict__ psum) {
  __shared__ int sh[256];
  int t = threadIdx.x;
  int i = blockIdx.x * 256 + t;
  int v = (i < NN) ? deg[i] : 0;
  sh[t] = v;
  __syncthreads();
  #pragma unroll
  for (int off = 1; off < 256; off <<= 1) {
    int t2 = (t >= off) ? sh[t - off] : 0;
    __syncthreads();
    sh[t] += t2;
    __syncthreads();
  }
  if (i < NN) rowptr[i + 1] = sh[t];
  if (t == 255) psum[blockIdx.x] = sh[255];
}

// per-block: inline scan of psum (196 entries) -> add exclusive prefix
__global__ __launch_bounds__(256)
void scanC_kernel(int* __restrict__ rowptr, const int* __restrict__ psum) {
  __shared__ int sh[256];
  int t = threadIdx.x;
  int v = (t < NB) ? psum[t] : 0;
  sh[t] = v;
  __syncthreads();
  #pragma unroll
  for (int off = 1; off < 256; off <<= 1) {
    int t2 = (t >= off) ? sh[t - off] : 0;
    __syncthreads();
    sh[t] += t2;
    __syncthreads();
  }
  int base = (blockIdx.x > 0) ? sh[blockIdx.x - 1] : 0;   // exclusive prefix
  int i = blockIdx.x * 256 + t;
  if (i < NN) rowptr[i + 1] += base;
  if (i == 0) rowptr[0] = 0;
}

__global__ __launch_bounds__(256)
void scatter_kernel(const int* __restrict__ srcs, const int* __restrict__ dsts,
                    const int* __restrict__ rowptr, int* __restrict__ cursor,
                    int* __restrict__ esrc) {
  int e = blockIdx.x * blockDim.x + threadIdx.x;
  if (e >= TOTE) return;
  int src, dst;
  if (e < EE) { src = srcs[e]; dst = dsts[e]; }
  else        { src = e - EE;  dst = e - EE; }
  int pos = rowptr[dst] + atomicAdd(&cursor[dst], 1);
  esrc[pos] = src;
}

// ------- agg layer 1, fused softmax (no max-sub): one wave per node ----------
// 2-edge unroll (two independent gather chains) — best measured form (R7).
__global__ __launch_bounds__(256)
void agg1_kernel(const ushort_t* __restrict__ H1bf, const float* __restrict__ AS,
                 const float* __restrict__ AD, const int* __restrict__ rowptr,
                 const int* __restrict__ esrc, const float* __restrict__ b1,
                 ushort_t* __restrict__ OUT) {
  int n = (blockIdx.x * blockDim.x + threadIdx.x) >> 6;
  int lane = threadIdx.x & 63;
  if (n >= NN) return;
  int off = lane * 8;
  int h = lane >> 3;
  float ad = AD[n * HEADS + h];
  int s0 = rowptr[n], s1 = rowptr[n + 1];
  float den = 0.f;
  float a0 = 0.f, a1 = 0.f, a2 = 0.f, a3 = 0.f, a4 = 0.f, a5 = 0.f, a6 = 0.f, a7 = 0.f;
  int j = s0;
  for (; j + 1 < s1; j += 2) {
    int srcA = esrc[j], srcB = esrc[j + 1];
    float asA = AS[srcA * HEADS + h];
    float asB = AS[srcB * HEADS + h];
    uint4 vA = *reinterpret_cast<const uint4*>(H1bf + (size_t)srcA * F1 + off);
    uint4 vB = *reinterpret_cast<const uint4*>(H1bf + (size_t)srcB * F1 + off);
    float wA = __expf(lrelu(asA + ad));
    float wB = __expf(lrelu(asB + ad));
    den += wA + wB;
    a0 = fmaf(wA, bf16lo_to_f32(vA.x), a0); a0 = fmaf(wB, bf16lo_to_f32(vB.x), a0);
    a1 = fmaf(wA, bf16hi_to_f32(vA.x), a1); a1 = fmaf(wB, bf16hi_to_f32(vB.x), a1);
    a2 = fmaf(wA, bf16lo_to_f32(vA.y), a2); a2 = fmaf(wB, bf16lo_to_f32(vB.y), a2);
    a3 = fmaf(wA, bf16hi_to_f32(vA.y), a3); a3 = fmaf(wB, bf16hi_to_f32(vB.y), a3);
    a4 = fmaf(wA, bf16lo_to_f32(vA.z), a4); a4 = fmaf(wB, bf16lo_to_f32(vB.z), a4);
    a5 = fmaf(wA, bf16hi_to_f32(vA.z), a5); a5 = fmaf(wB, bf16hi_to_f32(vB.z), a5);
    a6 = fmaf(wA, bf16lo_to_f32(vA.w), a6); a6 = fmaf(wB, bf16lo_to_f32(vB.w), a6);
    a7 = fmaf(wA, bf16hi_to_f32(vA.w), a7); a7 = fmaf(wB, bf16hi_to_f32(vB.w), a7);
  }
  if (j < s1) {
    int srcA = esrc[j];
    float asA = AS[srcA * HEADS + h];
    uint4 vA = *reinterpret_cast<const uint4*>(H1bf + (size_t)srcA * F1 + off);
    float wA = __expf(lrelu(asA + ad));
    den += wA;
    a0 = fmaf(wA, bf16lo_to_f32(vA.x), a0);
    a1 = fmaf(wA, bf16hi_to_f32(vA.x), a1);
    a2 = fmaf(wA, bf16lo_to_f32(vA.y), a2);
    a3 = fmaf(wA, bf16hi_to_f32(vA.y), a3);
    a4 = fmaf(wA, bf16lo_to_f32(vA.z), a4);
    a5 = fmaf(wA, bf16hi_to_f32(vA.z), a5);
    a6 = fmaf(wA, bf16lo_to_f32(vA.w), a6);
    a7 = fmaf(wA, bf16hi_to_f32(vA.w), a7);
  }
  float rden = 1.f / (den + 1e-16f);
  float4 b_lo = *reinterpret_cast<const float4*>(b1 + off);
  float4 b_hi = *reinterpret_cast<const float4*>(b1 + off + 4);
  float r[8];
  r[0] = fmaf(a0, rden, b_lo.x); r[1] = fmaf(a1, rden, b_lo.y);
  r[2] = fmaf(a2, rden, b_lo.z); r[3] = fmaf(a3, rden, b_lo.w);
  r[4] = fmaf(a4, rden, b_hi.x); r[5] = fmaf(a5, rden, b_hi.y);
  r[6] = fmaf(a6, rden, b_hi.z); r[7] = fmaf(a7, rden, b_hi.w);
  ushort_t pk[8];
  #pragma unroll
  for (int i = 0; i < 8; ++i) {
    float e = r[i] > 0.f ? r[i] : expm1f(r[i]);
    pk[i] = f32_to_bf16_rne(e);
  }
  *reinterpret_cast<uint4*>(OUT + (size_t)n * F1 + off) = *reinterpret_cast<uint4*>(pk);
}

// ------- agg layer 2, fused softmax: one wave per node, 8 edges in flight ----
__global__ __launch_bounds__(256)
void agg2_kernel(const ushort_t* __restrict__ H2bf, const float* __restrict__ AS,
                 const float* __restrict__ AD, const int* __restrict__ rowptr,
                 const int* __restrict__ esrc, const float* __restrict__ b2,
                 float* __restrict__ OUT) {
  int n = (blockIdx.x * blockDim.x + threadIdx.x) >> 6;
  int lane = threadIdx.x & 63;
  if (n >= NN) return;
  int grp = lane >> 3;
  int c8 = (lane & 7) * 8;
  float ad = AD[n];
  int s0 = rowptr[n], s1 = rowptr[n + 1];
  float den = 0.f;
  float a0 = 0.f, a1 = 0.f, a2 = 0.f, a3 = 0.f, a4 = 0.f, a5 = 0.f, a6 = 0.f, a7 = 0.f;
  for (int j0 = s0; j0 < s1; j0 += 8) {
    int j = j0 + grp;
    bool valid = j < s1;
    int src = esrc[valid ? j : s0];
    float as = AS[src];
    uint4 v = *reinterpret_cast<const uint4*>(H2bf + (size_t)src * OUTC + c8);
    float w = valid ? __expf(lrelu(as + ad)) : 0.f;
    den += w;
    a0 = fmaf(w, bf16lo_to_f32(v.x), a0);
    a1 = fmaf(w, bf16hi_to_f32(v.x), a1);
    a2 = fmaf(w, bf16lo_to_f32(v.y), a2);
    a3 = fmaf(w, bf16hi_to_f32(v.y), a3);
    a4 = fmaf(w, bf16lo_to_f32(v.z), a4);
    a5 = fmaf(w, bf16hi_to_f32(v.z), a5);
    a6 = fmaf(w, bf16lo_to_f32(v.w), a6);
    a7 = fmaf(w, bf16hi_to_f32(v.w), a7);
  }
  #pragma unroll
  for (int st = 8; st < 64; st <<= 1) {
    den += __shfl_xor(den, st);
    a0 += __shfl_xor(a0, st); a1 += __shfl_xor(a1, st);
    a2 += __shfl_xor(a2, st); a3 += __shfl_xor(a3, st);
    a4 += __shfl_xor(a4, st); a5 += __shfl_xor(a5, st);
    a6 += __shfl_xor(a6, st); a7 += __shfl_xor(a7, st);
  }
  if (grp == 0) {
    float rden = 1.f / (den + 1e-16f);
    float4 o0, o1;
    o0.x = fmaf(a0, rden, b2[c8 + 0]); o0.y = fmaf(a1, rden, b2[c8 + 1]);
    o0.z = fmaf(a2, rden, b2[c8 + 2]); o0.w = fmaf(a3, rden, b2[c8 + 3]);
    o1.x = fmaf(a4, rden, b2[c8 + 4]); o1.y = fmaf(a5, rden, b2[c8 + 5]);
    o1.z = fmaf(a6, rden, b2[c8 + 6]); o1.w = fmaf(a7, rden, b2[c8 + 7]);
    *reinterpret_cast<float4*>(OUT + (size_t)n * OUTC + c8) = o0;
    *reinterpret_cast<float4*>(OUT + (size_t)n * OUTC + c8 + 4) = o1;
  }
}

extern "C" void kernel_launch(void* const* d_in, const int* in_sizes, int n_in,
                              void* d_out, int out_size, void* d_ws, size_t ws_size,
                              hipStream_t stream) {
  const float* x      = (const float*)d_in[0];
  const int*   edges  = (const int*)d_in[1];   // [2, EE] int32
  const float* W1     = (const float*)d_in[2];
  const float* a_src1 = (const float*)d_in[3];
  const float* a_dst1 = (const float*)d_in[4];
  const float* b1     = (const float*)d_in[5];
  const float* W2     = (const float*)d_in[6];
  const float* a_src2 = (const float*)d_in[7];
  const float* a_dst2 = (const float*)d_in[8];
  const float* b2     = (const float*)d_in[9];
  float* out = (float*)d_out;

  const int* srcs = edges;
  const int* dsts = edges + EE;

  // ---- workspace layout ----
  float* AS1    = (float*)d_ws;                   // NN*HEADS (node-major)
  float* AD1    = AS1    + (size_t)NN * HEADS;
  float* AS2    = AD1    + (size_t)NN * HEADS;    // NN
  float* AD2    = AS2    + NN;
  ushort_t* xbf   = (ushort_t*)(AD2 + NN);        // NN*INC
  ushort_t* W1T   = xbf  + (size_t)NN * INC;      // F1*INC
  ushort_t* W2T   = W1T  + (size_t)F1 * INC;      // OUTC*F1
  ushort_t* H1bf  = W2T  + (size_t)OUTC * F1;     // NN*F1
  ushort_t* AG1bf = H1bf + (size_t)NN * F1;       // NN*F1
  ushort_t* H2bf  = AG1bf + (size_t)NN * F1;      // NN*OUTC
  int* deg    = (int*)(H2bf + (size_t)NN * OUTC); // NN
  int* rowptr = deg + NN;                         // NN+1
  int* cursor = rowptr + NN + 1;                  // NN
  int* psum   = cursor + NN;                      // NB
  int* esrc   = psum + NB;                        // TOTE

  hipMemsetAsync(deg, 0, (size_t)(3 * NN + 1) * sizeof(int), stream);

  // ---- fused prelude: conversions + degree count ----
  prelude_kernel<<<PB_CVTX + PB_CVTW1 + PB_CVTW2 + PB_COUNT, 256, 0, stream>>>(
      x, xbf, W1, W1T, W2, W2T, dsts, deg);

  // ---- CSR build ----
  scanA_kernel<<<NB, 256, 0, stream>>>(deg, rowptr, psum);
  scanC_kernel<<<NB, 256, 0, stream>>>(rowptr, psum);
  scatter_kernel<<<(TOTE + 255) / 256, 256, 0, stream>>>(srcs, dsts, rowptr, cursor, esrc);

  // ---- layer 1: GEMM (MFMA 128x128, fused alpha reduce) -> softmax-agg ----
  gemm_mfma128<<<((NN + 127) / 128) * (F1 / 128), 256, 0, stream>>>(
      xbf, W1T, a_src1, a_dst1, H1bf, AS1, AD1, NN, INC, F1, HEADS);
  agg1_kernel<<<(NN * 64 + 255) / 256, 256, 0, stream>>>(H1bf, AS1, AD1, rowptr, esrc, b1, AG1bf);

  // ---- layer 2: GEMM (MFMA 128x64) -> fused softmax-agg ----
  gemm_mfma<<<(NN + 127) / 128, 256, 0, stream>>>(
      AG1bf, W2T, a_src2, a_dst2, H2bf, AS2, AD2, NN, F1, OUTC, 1);
  agg2_kernel<<<(NN * 64 + 255) / 256, 256, 0, stream>>>(H2bf, AS2, AD2, rowptr, esrc, b2, out);
}

// Round 12
// 306.719 us; speedup vs baseline: 1.0273x; 1.0273x over previous
//
#include <hip/hip_runtime.h>
#include <cstddef>

#define NN   50000
#define EE   800000
#define TOTE 850000      // EE + NN self loops
#define INC  256
#define HEADS 8
#define F1   512         // HEADS*64
#define OUTC 64
#define NB   ((NN + 255) / 256)   // scan blocks = 196

// prelude partition (blocks)
#define PB_CVTX   ((NN * INC / 8 + 255) / 256)        // 6250
#define PB_CVTW1  ((INC * F1 + 255) / 256)            // 512
#define PB_CVTW2  ((F1 * OUTC + 255) / 256)           // 128
#define PB_COUNT  ((TOTE + 255) / 256)                // 3321

typedef unsigned short ushort_t;
typedef unsigned int uint_t;
typedef __attribute__((ext_vector_type(8))) short short8;
typedef __attribute__((ext_vector_type(4))) float f32x4;

__device__ __forceinline__ ushort_t f32_to_bf16_rne(float f) {
  uint_t u = __float_as_uint(f);
  u += 0x7fffu + ((u >> 16) & 1u);
  return (ushort_t)(u >> 16);
}
__device__ __forceinline__ float bf16lo_to_f32(uint_t u) {
  return __uint_as_float(u << 16);
}
__device__ __forceinline__ float bf16hi_to_f32(uint_t u) {
  return __uint_as_float(u & 0xffff0000u);
}
// leaky_relu(x, 0.2) = max(x, 0.2x)  (valid for slope<1)
__device__ __forceinline__ float lrelu(float x) { return fmaxf(x, 0.2f * x); }

// async global->LDS, 16B per lane; LDS dest is wave-uniform base + lane*16
__device__ __forceinline__ void gload16(const ushort_t* g, ushort_t* l) {
  __builtin_amdgcn_global_load_lds(
      (const __attribute__((address_space(1))) void*)g,
      (__attribute__((address_space(3))) void*)l, 16, 0, 0);
}

// ------- fused prelude: cvt_x | cvtT(W1) | cvtT(W2) | count (independent) ----
__global__ __launch_bounds__(256)
void prelude_kernel(const float* __restrict__ x, ushort_t* __restrict__ xbf,
                    const float* __restrict__ W1, ushort_t* __restrict__ W1T,
                    const float* __restrict__ W2, ushort_t* __restrict__ W2T,
                    const int* __restrict__ dsts, int* __restrict__ deg) {
  int b = blockIdx.x;
  if (b < PB_CVTX) {
    long i = ((long)b * 256 + threadIdx.x) * 8;
    if (i >= (long)NN * INC) return;
    float4 v0 = *reinterpret_cast<const float4*>(x + i);
    float4 v1 = *reinterpret_cast<const float4*>(x + i + 4);
    ushort_t p[8] = {f32_to_bf16_rne(v0.x), f32_to_bf16_rne(v0.y),
                     f32_to_bf16_rne(v0.z), f32_to_bf16_rne(v0.w),
                     f32_to_bf16_rne(v1.x), f32_to_bf16_rne(v1.y),
                     f32_to_bf16_rne(v1.z), f32_to_bf16_rne(v1.w)};
    *reinterpret_cast<uint4*>(xbf + i) = *reinterpret_cast<uint4*>(p);
    return;
  }
  b -= PB_CVTX;
  if (b < PB_CVTW1) {
    int i = b * 256 + threadIdx.x;
    if (i >= INC * F1) return;
    int k = i / F1, n = i % F1;
    W1T[(size_t)n * INC + k] = f32_to_bf16_rne(W1[i]);
    return;
  }
  b -= PB_CVTW1;
  if (b < PB_CVTW2) {
    int i = b * 256 + threadIdx.x;
    if (i >= F1 * OUTC) return;
    int k = i / OUTC, n = i % OUTC;
    W2T[(size_t)n * F1 + k] = f32_to_bf16_rne(W2[i]);
    return;
  }
  b -= PB_CVTW2;
  {
    int e = b * 256 + threadIdx.x;
    if (e >= TOTE) return;
    int dst = (e < EE) ? dsts[e] : (e - EE);
    atomicAdd(&deg[dst], 1);
  }
}

// ---- MFMA GEMM: C[M,Nn] = A[M,K] @ B[K,Nn], A bf16 [M,K], BT bf16 [Nn,K].
// BM=128, BN=64, BK=64, 4 waves. One 64-col block = one head.
__global__ __launch_bounds__(256, 2)
void gemm_mfma(const ushort_t* __restrict__ A, const ushort_t* __restrict__ BT,
               const float* __restrict__ a_src, const float* __restrict__ a_dst,
               ushort_t* __restrict__ Cbf, float* __restrict__ AS,
               float* __restrict__ AD, int M, int K, int Nn, int nheads) {
  __shared__ __align__(16) ushort_t sA[128 * 64];  // rows of 128B, slot-swizzled
  __shared__ __align__(16) ushort_t sB[64 * 64];
  const int tid = threadIdx.x;
  const int w = tid >> 6, lane = tid & 63;

  int p = blockIdx.x;
  int nwg = gridDim.x;
  int l = ((nwg & 7) == 0) ? ((p & 7) * (nwg >> 3) + (p >> 3)) : p;
  const int rowBase = (l / nheads) * 128;
  const int head = l % nheads;
  const int colBase = head * 64;

  const int l8 = lane >> 3;
  const int srcslot = (lane & 7) ^ l8;
  size_t aOff[4]; ushort_t* aLds[4];
  #pragma unroll
  for (int q = 0; q < 4; ++q) {
    int r0 = w * 32 + q * 8;
    int grow = rowBase + r0 + l8; if (grow > M - 1) grow = M - 1;
    aOff[q] = (size_t)grow * K + srcslot * 8;
    aLds[q] = sA + r0 * 64;
  }
  size_t bOff[2]; ushort_t* bLds[2];
  #pragma unroll
  for (int q = 0; q < 2; ++q) {
    int c0 = w * 16 + q * 8;
    bOff[q] = (size_t)(colBase + c0 + l8) * K + srcslot * 8;
    bLds[q] = sB + c0 * 64;
  }

  f32x4 acc[2][4];
  #pragma unroll
  for (int mf = 0; mf < 2; ++mf)
    #pragma unroll
    for (int cf = 0; cf < 4; ++cf)
      acc[mf][cf] = (f32x4){0.f, 0.f, 0.f, 0.f};

  const int nkt = K >> 6;
  for (int kt = 0; kt < nkt; ++kt) {
    __syncthreads();
    #pragma unroll
    for (int q = 0; q < 4; ++q) gload16(A + aOff[q] + kt * 64, aLds[q]);
    #pragma unroll
    for (int q = 0; q < 2; ++q) gload16(BT + bOff[q] + kt * 64, bLds[q]);
    __syncthreads();
    #pragma unroll
    for (int ks = 0; ks < 2; ++ks) {
      const int sl = ks * 4 + (lane >> 4);
      short8 af[2], bfr[4];
      #pragma unroll
      for (int mf = 0; mf < 2; ++mf) {
        int row = w * 32 + mf * 16 + (lane & 15);
        af[mf] = *reinterpret_cast<short8*>((char*)sA + row * 128 + ((sl ^ (row & 7)) << 4));
      }
      #pragma unroll
      for (int cf = 0; cf < 4; ++cf) {
        int col = cf * 16 + (lane & 15);
        bfr[cf] = *reinterpret_cast<short8*>((char*)sB + col * 128 + ((sl ^ (col & 7)) << 4));
      }
      #pragma unroll
      for (int mf = 0; mf < 2; ++mf)
        #pragma unroll
        for (int cf = 0; cf < 4; ++cf)
          acc[mf][cf] = __builtin_amdgcn_mfma_f32_16x16x32_bf16(af[mf], bfr[cf], acc[mf][cf], 0, 0, 0);
    }
  }

  const int g = lane >> 4, c = lane & 15;
  float asv[4], adv[4];
  #pragma unroll
  for (int cf = 0; cf < 4; ++cf) {
    asv[cf] = a_src[colBase + cf * 16 + c];
    adv[cf] = a_dst[colBase + cf * 16 + c];
  }
  #pragma unroll
  for (int mf = 0; mf < 2; ++mf) {
    #pragma unroll
    for (int r = 0; r < 4; ++r) {
      int row = rowBase + w * 32 + mf * 16 + g * 4 + r;
      bool ok = row < M;
      float s = 0.f, d = 0.f;
      #pragma unroll
      for (int cf = 0; cf < 4; ++cf) {
        float v = acc[mf][cf][r];
        s = fmaf(v, asv[cf], s);
        d = fmaf(v, adv[cf], d);
        if (ok) Cbf[(size_t)row * Nn + colBase + cf * 16 + c] = f32_to_bf16_rne(v);
      }
      #pragma unroll
      for (int off = 8; off > 0; off >>= 1) {
        s += __shfl_xor(s, off);
        d += __shfl_xor(d, off);
      }
      if (ok && c == 0) {
        AS[(size_t)row * nheads + head] = s;   // node-major
        AD[(size_t)row * nheads + head] = d;
      }
    }
  }
}

// ---------------- CSR build --------------------------------------------------
__global__ __launch_bounds__(256)
void scanA_kernel(const int* __restrict__ deg, int* __restrict__ rowptr,
                  int* __restrict__ psum) {
  __shared__ int sh[256];
  int t = threadIdx.x;
  int i = blockIdx.x * 256 + t;
  int v = (i < NN) ? deg[i] : 0;
  sh[t] = v;
  __syncthreads();
  #pragma unroll
  for (int off = 1; off < 256; off <<= 1) {
    int t2 = (t >= off) ? sh[t - off] : 0;
    __syncthreads();
    sh[t] += t2;
    __syncthreads();
  }
  if (i < NN) rowptr[i + 1] = sh[t];
  if (t == 255) psum[blockIdx.x] = sh[255];
}

// per-block: inline scan of psum (196 entries) -> add exclusive prefix
__global__ __launch_bounds__(256)
void scanC_kernel(int* __restrict__ rowptr, const int* __restrict__ psum) {
  __shared__ int sh[256];
  int t = threadIdx.x;
  int v = (t < NB) ? psum[t] : 0;
  sh[t] = v;
  __syncthreads();
  #pragma unroll
  for (int off = 1; off < 256; off <<= 1) {
    int t2 = (t >= off) ? sh[t - off] : 0;
    __syncthreads();
    sh[t] += t2;
    __syncthreads();
  }
  int base = (blockIdx.x > 0) ? sh[blockIdx.x - 1] : 0;   // exclusive prefix
  int i = blockIdx.x * 256 + t;
  if (i < NN) rowptr[i + 1] += base;
  if (i == 0) rowptr[0] = 0;
}

__global__ __launch_bounds__(256)
void scatter_kernel(const int* __restrict__ srcs, const int* __restrict__ dsts,
                    const int* __restrict__ rowptr, int* __restrict__ cursor,
                    int* __restrict__ esrc) {
  int e = blockIdx.x * blockDim.x + threadIdx.x;
  if (e >= TOTE) return;
  int src, dst;
  if (e < EE) { src = srcs[e]; dst = dsts[e]; }
  else        { src = e - EE;  dst = e - EE; }
  int pos = rowptr[dst] + atomicAdd(&cursor[dst], 1);
  esrc[pos] = src;
}

// ------- agg layer 1, fused softmax (no max-sub): one wave per node ----------
// 2-edge unroll (two independent gather chains) — best measured form (R7).
__global__ __launch_bounds__(256)
void agg1_kernel(const ushort_t* __restrict__ H1bf, const float* __restrict__ AS,
                 const float* __restrict__ AD, const int* __restrict__ rowptr,
                 const int* __restrict__ esrc, const float* __restrict__ b1,
                 ushort_t* __restrict__ OUT) {
  int n = (blockIdx.x * blockDim.x + threadIdx.x) >> 6;
  int lane = threadIdx.x & 63;
  if (n >= NN) return;
  int off = lane * 8;
  int h = lane >> 3;
  float ad = AD[n * HEADS + h];
  int s0 = rowptr[n], s1 = rowptr[n + 1];
  float den = 0.f;
  float a0 = 0.f, a1 = 0.f, a2 = 0.f, a3 = 0.f, a4 = 0.f, a5 = 0.f, a6 = 0.f, a7 = 0.f;
  int j = s0;
  for (; j + 1 < s1; j += 2) {
    int srcA = esrc[j], srcB = esrc[j + 1];
    float asA = AS[srcA * HEADS + h];
    float asB = AS[srcB * HEADS + h];
    uint4 vA = *reinterpret_cast<const uint4*>(H1bf + (size_t)srcA * F1 + off);
    uint4 vB = *reinterpret_cast<const uint4*>(H1bf + (size_t)srcB * F1 + off);
    float wA = __expf(lrelu(asA + ad));
    float wB = __expf(lrelu(asB + ad));
    den += wA + wB;
    a0 = fmaf(wA, bf16lo_to_f32(vA.x), a0); a0 = fmaf(wB, bf16lo_to_f32(vB.x), a0);
    a1 = fmaf(wA, bf16hi_to_f32(vA.x), a1); a1 = fmaf(wB, bf16hi_to_f32(vB.x), a1);
    a2 = fmaf(wA, bf16lo_to_f32(vA.y), a2); a2 = fmaf(wB, bf16lo_to_f32(vB.y), a2);
    a3 = fmaf(wA, bf16hi_to_f32(vA.y), a3); a3 = fmaf(wB, bf16hi_to_f32(vB.y), a3);
    a4 = fmaf(wA, bf16lo_to_f32(vA.z), a4); a4 = fmaf(wB, bf16lo_to_f32(vB.z), a4);
    a5 = fmaf(wA, bf16hi_to_f32(vA.z), a5); a5 = fmaf(wB, bf16hi_to_f32(vB.z), a5);
    a6 = fmaf(wA, bf16lo_to_f32(vA.w), a6); a6 = fmaf(wB, bf16lo_to_f32(vB.w), a6);
    a7 = fmaf(wA, bf16hi_to_f32(vA.w), a7); a7 = fmaf(wB, bf16hi_to_f32(vB.w), a7);
  }
  if (j < s1) {
    int srcA = esrc[j];
    float asA = AS[srcA * HEADS + h];
    uint4 vA = *reinterpret_cast<const uint4*>(H1bf + (size_t)srcA * F1 + off);
    float wA = __expf(lrelu(asA + ad));
    den += wA;
    a0 = fmaf(wA, bf16lo_to_f32(vA.x), a0);
    a1 = fmaf(wA, bf16hi_to_f32(vA.x), a1);
    a2 = fmaf(wA, bf16lo_to_f32(vA.y), a2);
    a3 = fmaf(wA, bf16hi_to_f32(vA.y), a3);
    a4 = fmaf(wA, bf16lo_to_f32(vA.z), a4);
    a5 = fmaf(wA, bf16hi_to_f32(vA.z), a5);
    a6 = fmaf(wA, bf16lo_to_f32(vA.w), a6);
    a7 = fmaf(wA, bf16hi_to_f32(vA.w), a7);
  }
  float rden = 1.f / (den + 1e-16f);
  float4 b_lo = *reinterpret_cast<const float4*>(b1 + off);
  float4 b_hi = *reinterpret_cast<const float4*>(b1 + off + 4);
  float r[8];
  r[0] = fmaf(a0, rden, b_lo.x); r[1] = fmaf(a1, rden, b_lo.y);
  r[2] = fmaf(a2, rden, b_lo.z); r[3] = fmaf(a3, rden, b_lo.w);
  r[4] = fmaf(a4, rden, b_hi.x); r[5] = fmaf(a5, rden, b_hi.y);
  r[6] = fmaf(a6, rden, b_hi.z); r[7] = fmaf(a7, rden, b_hi.w);
  ushort_t pk[8];
  #pragma unroll
  for (int i = 0; i < 8; ++i) {
    float e = r[i] > 0.f ? r[i] : expm1f(r[i]);
    pk[i] = f32_to_bf16_rne(e);
  }
  *reinterpret_cast<uint4*>(OUT + (size_t)n * F1 + off) = *reinterpret_cast<uint4*>(pk);
}

// ------- agg layer 2, fused softmax: one wave per node, 8 edges in flight ----
__global__ __launch_bounds__(256)
void agg2_kernel(const ushort_t* __restrict__ H2bf, const float* __restrict__ AS,
                 const float* __restrict__ AD, const int* __restrict__ rowptr,
                 const int* __restrict__ esrc, const float* __restrict__ b2,
                 float* __restrict__ OUT) {
  int n = (blockIdx.x * blockDim.x + threadIdx.x) >> 6;
  int lane = threadIdx.x & 63;
  if (n >= NN) return;
  int grp = lane >> 3;
  int c8 = (lane & 7) * 8;
  float ad = AD[n];
  int s0 = rowptr[n], s1 = rowptr[n + 1];
  float den = 0.f;
  float a0 = 0.f, a1 = 0.f, a2 = 0.f, a3 = 0.f, a4 = 0.f, a5 = 0.f, a6 = 0.f, a7 = 0.f;
  for (int j0 = s0; j0 < s1; j0 += 8) {
    int j = j0 + grp;
    bool valid = j < s1;
    int src = esrc[valid ? j : s0];
    float as = AS[src];
    uint4 v = *reinterpret_cast<const uint4*>(H2bf + (size_t)src * OUTC + c8);
    float w = valid ? __expf(lrelu(as + ad)) : 0.f;
    den += w;
    a0 = fmaf(w, bf16lo_to_f32(v.x), a0);
    a1 = fmaf(w, bf16hi_to_f32(v.x), a1);
    a2 = fmaf(w, bf16lo_to_f32(v.y), a2);
    a3 = fmaf(w, bf16hi_to_f32(v.y), a3);
    a4 = fmaf(w, bf16lo_to_f32(v.z), a4);
    a5 = fmaf(w, bf16hi_to_f32(v.z), a5);
    a6 = fmaf(w, bf16lo_to_f32(v.w), a6);
    a7 = fmaf(w, bf16hi_to_f32(v.w), a7);
  }
  #pragma unroll
  for (int st = 8; st < 64; st <<= 1) {
    den += __shfl_xor(den, st);
    a0 += __shfl_xor(a0, st); a1 += __shfl_xor(a1, st);
    a2 += __shfl_xor(a2, st); a3 += __shfl_xor(a3, st);
    a4 += __shfl_xor(a4, st); a5 += __shfl_xor(a5, st);
    a6 += __shfl_xor(a6, st); a7 += __shfl_xor(a7, st);
  }
  if (grp == 0) {
    float rden = 1.f / (den + 1e-16f);
    float4 o0, o1;
    o0.x = fmaf(a0, rden, b2[c8 + 0]); o0.y = fmaf(a1, rden, b2[c8 + 1]);
    o0.z = fmaf(a2, rden, b2[c8 + 2]); o0.w = fmaf(a3, rden, b2[c8 + 3]);
    o1.x = fmaf(a4, rden, b2[c8 + 4]); o1.y = fmaf(a5, rden, b2[c8 + 5]);
    o1.z = fmaf(a6, rden, b2[c8 + 6]); o1.w = fmaf(a7, rden, b2[c8 + 7]);
    *reinterpret_cast<float4*>(OUT + (size_t)n * OUTC + c8) = o0;
    *reinterpret_cast<float4*>(OUT + (size_t)n * OUTC + c8 + 4) = o1;
  }
}

extern "C" void kernel_launch(void* const* d_in, const int* in_sizes, int n_in,
                              void* d_out, int out_size, void* d_ws, size_t ws_size,
                              hipStream_t stream) {
  const float* x      = (const float*)d_in[0];
  const int*   edges  = (const int*)d_in[1];   // [2, EE] int32
  const float* W1     = (const float*)d_in[2];
  const float* a_src1 = (const float*)d_in[3];
  const float* a_dst1 = (const float*)d_in[4];
  const float* b1     = (const float*)d_in[5];
  const float* W2     = (const float*)d_in[6];
  const float* a_src2 = (const float*)d_in[7];
  const float* a_dst2 = (const float*)d_in[8];
  const float* b2     = (const float*)d_in[9];
  float* out = (float*)d_out;

  const int* srcs = edges;
  const int* dsts = edges + EE;

  // ---- workspace layout ----
  float* AS1    = (float*)d_ws;                   // NN*HEADS (node-major)
  float* AD1    = AS1    + (size_t)NN * HEADS;
  float* AS2    = AD1    + (size_t)NN * HEADS;    // NN
  float* AD2    = AS2    + NN;
  ushort_t* xbf   = (ushort_t*)(AD2 + NN);        // NN*INC
  ushort_t* W1T   = xbf  + (size_t)NN * INC;      // F1*INC
  ushort_t* W2T   = W1T  + (size_t)F1 * INC;      // OUTC*F1
  ushort_t* H1bf  = W2T  + (size_t)OUTC * F1;     // NN*F1
  ushort_t* AG1bf = H1bf + (size_t)NN * F1;       // NN*F1
  ushort_t* H2bf  = AG1bf + (size_t)NN * F1;      // NN*OUTC
  int* deg    = (int*)(H2bf + (size_t)NN * OUTC); // NN
  int* rowptr = deg + NN;                         // NN+1
  int* cursor = rowptr + NN + 1;                  // NN
  int* psum   = cursor + NN;                      // NB
  int* esrc   = psum + NB;                        // TOTE

  hipMemsetAsync(deg, 0, (size_t)(3 * NN + 1) * sizeof(int), stream);

  // ---- fused prelude: conversions + degree count ----
  prelude_kernel<<<PB_CVTX + PB_CVTW1 + PB_CVTW2 + PB_COUNT, 256, 0, stream>>>(
      x, xbf, W1, W1T, W2, W2T, dsts, deg);

  // ---- CSR build ----
  scanA_kernel<<<NB, 256, 0, stream>>>(deg, rowptr, psum);
  scanC_kernel<<<NB, 256, 0, stream>>>(rowptr, psum);
  scatter_kernel<<<(TOTE + 255) / 256, 256, 0, stream>>>(srcs, dsts, rowptr, cursor, esrc);

  // ---- layer 1: GEMM (MFMA, fused alpha reduce) -> fused softmax-agg ----
  gemm_mfma<<<((NN + 127) / 128) * HEADS, 256, 0, stream>>>(
      xbf, W1T, a_src1, a_dst1, H1bf, AS1, AD1, NN, INC, F1, HEADS);
  agg1_kernel<<<(NN * 64 + 255) / 256, 256, 0, stream>>>(H1bf, AS1, AD1, rowptr, esrc, b1, AG1bf);

  // ---- layer 2: GEMM (MFMA) -> fused softmax-agg ----
  gemm_mfma<<<(NN + 127) / 128, 256, 0, stream>>>(
      AG1bf, W2T, a_src2, a_dst2, H2bf, AS2, AD2, NN, F1, OUTC, 1);
  agg2_kernel<<<(NN * 64 + 255) / 256, 256, 0, stream>>>(H2bf, AS2, AD2, rowptr, esrc, b2, out);
}